// Round 4
// baseline (120.999 us; speedup 1.0000x reference)
//
#include <hip/hip_runtime.h>

#define G_TOTAL 16384            // 128 x 128 grid
#define NPTS    8192
#define SPLITS  64               // split-K over i for the GEMV stage
#define PSTRIDE (128 * 3 * 128)  // 49152 floats per split partial

// ws partition (float offsets). Total 33.6 MB << 256 MB workspace.
#define EX_OFF  0u               // Ex[8192][128]    : 1M floats (4 MB)
#define B_OFF   (1u << 20)       // B[32][8192][16]  : 4M floats (16 MB)
#define P_OFF   (B_OFF + (1u << 22))  // partials [64][128*3][128] : 3M floats

// Raw v_exp_f32 — args in [-55, 0]: no range fixup needed.
__device__ __forceinline__ float fast_exp2(float x) {
#if __has_builtin(__builtin_amdgcn_exp2f)
    return __builtin_amdgcn_exp2f(x);
#else
    float r; asm("v_exp_f32 %0, %1" : "=v"(r) : "v"(x)); return r;
#endif
}

// ---------------------------------------------------------------------------
// Stage A: build both factor tables (each exp computed exactly once, 2M total).
//   Ex[i][j]          = exp2(-(s*(gx_j - x_i))^2)                  (4 MB)
//   B[q][i][16]       = {e_u, e_u*y0, e_u*y1 : u=0..3} + 4 pad     (16 MB)
//                       e_u = exp2(-(s*(gy_{4q+u} - xy_i))^2)
// Channel expansion is baked here so the GEMV inner loop is pure fma.
// ---------------------------------------------------------------------------
__global__ __launch_bounds__(256) void gen_tables(
    const float* __restrict__ X, const float* __restrict__ Y,
    float* __restrict__ ws)
{
    const float s    = 0.84932184f;      // sqrt(0.5 * log2(e))
    const float step = 4.0f / 127.0f;
    const int   t    = blockIdx.x * 256 + threadIdx.x;   // 0..262143

    if (blockIdx.y == 0) {
        // Ex: thread -> (i, 4-wide j group). 32 threads share one x_i (L1 hit).
        const int   i  = t >> 5, jg = t & 31;
        const float xs = X[2 * i] * s;
        const float ss = step * s;
        const float d0 = (-2.0f + step * (float)(jg * 4)) * s - xs;
        float4 v;
        v.x = fast_exp2(-d0 * d0);
        const float d1 = d0 + ss;        v.y = fast_exp2(-d1 * d1);
        const float d2 = d0 + 2.f * ss;  v.z = fast_exp2(-d2 * d2);
        const float d3 = d0 + 3.f * ss;  v.w = fast_exp2(-d3 * d3);
        *(float4*)&ws[EX_OFF + i * 128 + jg * 4] = v;
    } else {
        // B: thread -> (q, i)
        const int    q  = t >> 13, i = t & 8191;
        const float  ys = X[2 * i + 1] * s;
        const float2 w  = ((const float2*)Y)[i];
        float e[4];
#pragma unroll
        for (int u = 0; u < 4; ++u) {
            const float gy = (2.0f - step * (float)(q * 4 + u)) * s;
            const float d  = gy - ys;
            e[u] = fast_exp2(-d * d);
        }
        float* base = &ws[B_OFF + ((unsigned)(q * 8192 + i) << 4)];
        *(float4*)(base + 0) = make_float4(e[0], e[0]*w.x, e[0]*w.y, e[1]);
        *(float4*)(base + 4) = make_float4(e[1]*w.x, e[1]*w.y, e[2], e[2]*w.x);
        *(float4*)(base + 8) = make_float4(e[2]*w.y, e[3], e[3]*w.x, e[3]*w.y);
    }
}

// ---------------------------------------------------------------------------
// Stage B: scalar-broadcast GEMV. Block = (i-slab bx, k-quad q). 4 waves:
// lane <-> j (jw picks j half), isub (wave-uniform, readfirstlane'd) picks
// the 128-i half-slab. Per i: 1 coalesced b32 A-load (L2-resident table),
// 48 B of wave-uniform B via the scalar pipe, 12 fma. No LDS, no exp.
// ---------------------------------------------------------------------------
__global__ __launch_bounds__(256) void gemv_kernel(float* __restrict__ ws)
{
    const int t     = threadIdx.x;
    const int lane  = t & 63;
    const int jw    = (t >> 6) & 1;
    const int isub  = __builtin_amdgcn_readfirstlane(t >> 7);  // wave-uniform
    const int q     = blockIdx.y;                    // k-quad 0..31
    const int iBase = blockIdx.x * 256 + isub * 128; // 128-i range
    const int isplit = blockIdx.x * 2 + isub;        // 0..63

    const float* __restrict__ A =
        ws + EX_OFF + (unsigned)iBase * 128 + jw * 64 + lane;
    const float4* __restrict__ B =
        (const float4*)(ws + B_OFF) + ((unsigned)(q * 8192 + iBase) << 2);

    float acc[12];
#pragma unroll
    for (int z = 0; z < 12; ++z) acc[z] = 0.0f;

#pragma unroll 4
    for (int i = 0; i < 128; ++i) {
        const float  a  = A[i * 128];      // 256B coalesced, imm-offset in unroll
        const float4 b0 = B[i * 4 + 0];    // wave-uniform -> s_load
        const float4 b1 = B[i * 4 + 1];
        const float4 b2 = B[i * 4 + 2];
        acc[0]  = fmaf(a, b0.x, acc[0]);   // u0: e0, e0*y0, e0*y1
        acc[1]  = fmaf(a, b0.y, acc[1]);
        acc[2]  = fmaf(a, b0.z, acc[2]);
        acc[3]  = fmaf(a, b0.w, acc[3]);   // u1
        acc[4]  = fmaf(a, b1.x, acc[4]);
        acc[5]  = fmaf(a, b1.y, acc[5]);
        acc[6]  = fmaf(a, b1.z, acc[6]);   // u2
        acc[7]  = fmaf(a, b1.w, acc[7]);
        acc[8]  = fmaf(a, b2.x, acc[8]);
        acc[9]  = fmaf(a, b2.y, acc[9]);   // u3
        acc[10] = fmaf(a, b2.z, acc[10]);
        acc[11] = fmaf(a, b2.w, acc[11]);
    }

    // partial store: [isplit][k*3+c][j], coalesced 256B per (u,c)
    float* P = ws + P_OFF + (unsigned)isplit * PSTRIDE
             + (unsigned)(q * 4) * 384 + jw * 64 + lane;
#pragma unroll
    for (int u = 0; u < 4; ++u)
#pragma unroll
        for (int c = 0; c < 3; ++c)
            P[u * 384 + c * 128] = acc[u * 3 + c];
}

// ---------------------------------------------------------------------------
// Stage C: 64-way split-K sum + normalize. Thread <-> grid point (k,j);
// 3 channel streams, coalesced in j; 24 loads in flight via unroll.
// ---------------------------------------------------------------------------
__global__ __launch_bounds__(256) void reduce_norm(
    const float* __restrict__ ws, float* __restrict__ out)
{
    const int g = blockIdx.x * 256 + threadIdx.x;    // k*128 + j
    const int k = g >> 7, j = g & 127;
    const float* p = ws + P_OFF + (unsigned)(k * 384 + j);

    float s0 = 0.f, s1 = 0.f, s2 = 0.f;
#pragma unroll 8
    for (int s = 0; s < SPLITS; ++s) {
        const float* b = p + (unsigned)s * PSTRIDE;
        s0 += b[0];
        s1 += b[128];
        s2 += b[256];
    }
    const float inv = 1.0f / s0;
    out[g]               = s0;
    out[G_TOTAL + g]     = s1 * inv;
    out[2 * G_TOTAL + g] = s2 * inv;
}

// ---------------------------------------------------------------------------
extern "C" void kernel_launch(void* const* d_in, const int* in_sizes, int n_in,
                              void* d_out, int out_size, void* d_ws, size_t ws_size,
                              hipStream_t stream) {
    const float* X = (const float*)d_in[0];
    const float* Y = (const float*)d_in[1];
    float* out = (float*)d_out;
    float* ws  = (float*)d_ws;

    gen_tables<<<dim3(1024, 2), 256, 0, stream>>>(X, Y, ws);
    gemv_kernel<<<dim3(32, 32), 256, 0, stream>>>(ws);
    reduce_norm<<<G_TOTAL / 256, 256, 0, stream>>>(ws, out);
}

// Round 5
// 114.259 us; speedup vs baseline: 1.0590x; 1.0590x over previous
//
#include <hip/hip_runtime.h>

#define G_TOTAL 16384            // 128 x 128 grid
#define NPTS    8192
#define SPLITS  128              // split-K over i for the GEMV stage
#define PSTRIDE 49152            // floats per split partial: 128k * 3c * 128j

// ws partition (float offsets). Total ~45 MB << 256 MB workspace.
#define EX4_OFF 0u                        // Ex4[2048][128][4] : 4 MB
#define B_OFF   (1u << 20)                // B[32][8192][16]   : 16 MB
#define P_OFF   (B_OFF + (1u << 22))      // partials [128][49152] : 25 MB

// Raw v_exp_f32 — args in [-55, 0]: no range fixup needed.
__device__ __forceinline__ float fast_exp2(float x) {
#if __has_builtin(__builtin_amdgcn_exp2f)
    return __builtin_amdgcn_exp2f(x);
#else
    float r; asm("v_exp_f32 %0, %1" : "=v"(r) : "v"(x)); return r;
#endif
}

// ---------------------------------------------------------------------------
// Stage A: factor tables, each exp computed once (2M total).
//   Ex4[ib][j][e] = exp2(-(s*(gx_j - x_{4ib+e}))^2)   (float4 per (ib,j))
//   B[q][i][16]   = {e_u, e_u*y0, e_u*y1 : u=0..3} + pad,  e_u over k=4q+u
// A is packed 4-i-per-float4 so the GEMV does one b128 A-load per 4 i.
// ---------------------------------------------------------------------------
__global__ __launch_bounds__(256) void gen_tables(
    const float* __restrict__ X, const float* __restrict__ Y,
    float* __restrict__ ws)
{
    const float s    = 0.84932184f;      // sqrt(0.5 * log2(e))
    const float step = 4.0f / 127.0f;
    const int   t    = blockIdx.x * 256 + threadIdx.x;   // 0..262143

    if (blockIdx.y == 0) {
        // Ex4: thread -> (ib, j). 128 threads share the same 4 x_i (L1 hit).
        const int   ib = t >> 7, j = t & 127;
        const float gx = (-2.0f + step * (float)j) * s;
        float4 v;
        {
            const float d0 = gx - X[8 * ib + 0] * s;  v.x = fast_exp2(-d0 * d0);
            const float d1 = gx - X[8 * ib + 2] * s;  v.y = fast_exp2(-d1 * d1);
            const float d2 = gx - X[8 * ib + 4] * s;  v.z = fast_exp2(-d2 * d2);
            const float d3 = gx - X[8 * ib + 6] * s;  v.w = fast_exp2(-d3 * d3);
        }
        ((float4*)(ws + EX4_OFF))[ib * 128 + j] = v;
    } else {
        // B: thread -> (q, i), channel expansion baked in.
        const int    q  = t >> 13, i = t & 8191;
        const float  ys = X[2 * i + 1] * s;
        const float2 w  = ((const float2*)Y)[i];
        float e[4];
#pragma unroll
        for (int u = 0; u < 4; ++u) {
            const float gy = (2.0f - step * (float)(q * 4 + u)) * s;
            const float d  = gy - ys;
            e[u] = fast_exp2(-d * d);
        }
        float* base = &ws[B_OFF + ((unsigned)(q * 8192 + i) << 4)];
        *(float4*)(base +  0) = make_float4(e[0], e[0]*w.x, e[0]*w.y, e[1]);
        *(float4*)(base +  4) = make_float4(e[1]*w.x, e[1]*w.y, e[2], e[2]*w.x);
        *(float4*)(base +  8) = make_float4(e[2]*w.y, e[3], e[3]*w.x, e[3]*w.y);
        *(float4*)(base + 12) = make_float4(0.f, 0.f, 0.f, 0.f);   // pad
    }
}

// ---------------------------------------------------------------------------
// Stage B: scalar-broadcast GEMV, depth-2 pipelined.
// Block (bx, q): 4 waves; lane<->j (jw half), isub (uniform) picks 64-i slab.
// Per 4-i group: 1 b128 A-load (VMEM) + 12 uniform float4 (SMEM) + 48 fma.
// Explicit a0/a1/p0/p1 prefetch forces 2-group load depth; 2048 blocks ->
// 8 blocks/CU, 32 waves/CU for TLP on top.
// ---------------------------------------------------------------------------
#define GROUP4(aV, Bg)                                                        \
    {                                                                         \
        _Pragma("unroll")                                                     \
        for (int e = 0; e < 4; ++e) {                                         \
            const float  av = (e == 0) ? aV.x : (e == 1) ? aV.y               \
                            : (e == 2) ? aV.z : aV.w;                         \
            const float4 b0 = *(const float4*)((Bg) + (e << 4) + 0);          \
            const float4 b1 = *(const float4*)((Bg) + (e << 4) + 4);          \
            const float4 b2 = *(const float4*)((Bg) + (e << 4) + 8);          \
            acc[0]  = fmaf(av, b0.x, acc[0]);                                 \
            acc[1]  = fmaf(av, b0.y, acc[1]);                                 \
            acc[2]  = fmaf(av, b0.z, acc[2]);                                 \
            acc[3]  = fmaf(av, b0.w, acc[3]);                                 \
            acc[4]  = fmaf(av, b1.x, acc[4]);                                 \
            acc[5]  = fmaf(av, b1.y, acc[5]);                                 \
            acc[6]  = fmaf(av, b1.z, acc[6]);                                 \
            acc[7]  = fmaf(av, b1.w, acc[7]);                                 \
            acc[8]  = fmaf(av, b2.x, acc[8]);                                 \
            acc[9]  = fmaf(av, b2.y, acc[9]);                                 \
            acc[10] = fmaf(av, b2.z, acc[10]);                                \
            acc[11] = fmaf(av, b2.w, acc[11]);                                \
        }                                                                     \
    }

__global__ __launch_bounds__(256, 8) void gemv_kernel(float* __restrict__ ws)
{
    const int t      = threadIdx.x;
    const int lane   = t & 63;
    const int jw     = (t >> 6) & 1;
    const int isub   = __builtin_amdgcn_readfirstlane(t >> 7);  // wave-uniform
    const int q      = blockIdx.y;                  // k-quad 0..31
    const int bx     = blockIdx.x;                  // 0..63
    const int iBase  = bx * 128 + isub * 64;        // 64-i slab
    const int isplit = bx * 2 + isub;               // 0..127

    const float4* __restrict__ A4 =
        (const float4*)(ws + EX4_OFF) + (unsigned)(iBase >> 2) * 128 + jw * 64 + lane;
    const float* __restrict__ Bb =
        ws + B_OFF + ((unsigned)(q * 8192 + iBase) << 4);       // uniform

    float acc[12];
#pragma unroll
    for (int z = 0; z < 12; ++z) acc[z] = 0.0f;

    float4 a0 = A4[0];
    float4 a1 = A4[128];

#pragma unroll
    for (int g = 0; g < 16; g += 2) {
        const float4 p0 = (g + 2 < 16) ? A4[(g + 2) * 128] : a0;  // prefetch
        const float4 p1 = (g + 3 < 16) ? A4[(g + 3) * 128] : a1;
        const float* Bg0 = Bb + (g << 6);           // 64 floats per 4-i group
        GROUP4(a0, Bg0);
        GROUP4(a1, Bg0 + 64);
        a0 = p0;
        a1 = p1;
    }

    // partial store: [isplit][k][c][j], coalesced 256B per (u,c)
    float* P = ws + P_OFF + (size_t)isplit * PSTRIDE
             + (unsigned)(q * 4) * 384 + jw * 64 + lane;
#pragma unroll
    for (int u = 0; u < 4; ++u)
#pragma unroll
        for (int c = 0; c < 3; ++c)
            P[u * 384 + c * 128] = acc[u * 3 + c];
}

// ---------------------------------------------------------------------------
// Stage C: split-K sum + normalize. Block = 64 grid points x 4 split-quarters
// (each thread sums 32 splits x 3 channels, coalesced in j), LDS combine,
// lanes 0..63 normalize + write. 256 blocks -> 1/CU.
// ---------------------------------------------------------------------------
__global__ __launch_bounds__(256) void reduce_norm(
    const float* __restrict__ ws, float* __restrict__ out)
{
    __shared__ float sm[4][3][64];
    const int t  = threadIdx.x;
    const int p  = t & 63;
    const int sq = t >> 6;
    const int g0 = blockIdx.x * 64 + p;
    const int k  = g0 >> 7, j = g0 & 127;

    const float* base = ws + P_OFF + (unsigned)(k * 3) * 128 + j;
    float s0 = 0.f, s1 = 0.f, s2 = 0.f;
#pragma unroll 4
    for (int sp = sq * 32; sp < sq * 32 + 32; ++sp) {
        const float* b = base + (size_t)sp * PSTRIDE;
        s0 += b[0];
        s1 += b[128];
        s2 += b[256];
    }
    sm[sq][0][p] = s0; sm[sq][1][p] = s1; sm[sq][2][p] = s2;
    __syncthreads();

    if (t < 64) {
        const float r0 = sm[0][0][t] + sm[1][0][t] + sm[2][0][t] + sm[3][0][t];
        const float r1 = sm[0][1][t] + sm[1][1][t] + sm[2][1][t] + sm[3][1][t];
        const float r2 = sm[0][2][t] + sm[1][2][t] + sm[2][2][t] + sm[3][2][t];
        const int   g   = blockIdx.x * 64 + t;
        const float inv = 1.0f / r0;
        out[g]               = r0;
        out[G_TOTAL + g]     = r1 * inv;
        out[2 * G_TOTAL + g] = r2 * inv;
    }
}

// ---------------------------------------------------------------------------
extern "C" void kernel_launch(void* const* d_in, const int* in_sizes, int n_in,
                              void* d_out, int out_size, void* d_ws, size_t ws_size,
                              hipStream_t stream) {
    const float* X = (const float*)d_in[0];
    const float* Y = (const float*)d_in[1];
    float* out = (float*)d_out;
    float* ws  = (float*)d_ws;

    gen_tables<<<dim3(1024, 2), 256, 0, stream>>>(X, Y, ws);
    gemv_kernel<<<dim3(64, 32), 256, 0, stream>>>(ws);
    reduce_norm<<<G_TOTAL / 64, 256, 0, stream>>>(ws, out);
}

// Round 6
// 85.159 us; speedup vs baseline: 1.4209x; 1.3417x over previous
//
#include <hip/hip_runtime.h>

#define G_TOTAL 16384            // 128 x 128 grid
#define NPTS    8192
#define CI      64               // context points per block
#define NSPLIT  128              // 8192 / CI
#define BJ      128              // j extent per block (TJ=4 x 32 frags)
#define BK      32               // k extent per block (TK=4 x 8 frags)
#define PBLK    12288            // partial floats per block: 128*32*3
// ws: partials [4 tiles][128 s][12288] = 25 MB (float offsets, P at 0)

// Raw v_exp_f32 — args in [-30, 0]: no denormal/range fixup needed.
__device__ __forceinline__ float fast_exp2(float x) {
#if __has_builtin(__builtin_amdgcn_exp2f)
    return __builtin_amdgcn_exp2f(x);
#else
    float r; asm("v_exp_f32 %0, %1" : "=v"(r) : "v"(x)); return r;
#endif
}

// ---------------------------------------------------------------------------
// Fused factorized kernel. w(j,k,i) = Ex(j,i)*Ey(k,i); channels {1,y0,y1}.
// R5 post-mortem: SMEM/global operand streaming = serial latency chain
// (VALUBusy 10%). Back to the R2 LDS structure with the ratio fixed:
// TJ=4 x TK=4 x 3ch = 48 acc/thread -> per i: 1 per-lane b128 + 1 broadcast
// b128 + 1 uniform b64 (~30 LDS-cy) vs 56 VALU instr (28 CU-cy). Balanced.
// Block: 256 thr = 32 jf x 8 kf; tile 128j x 32k; CI=64 -> grid 512
// (2 blocks/CU, 8 waves/CU), LDS 41.3 KB. Exps fused (32+8 per thread).
// Epilogue: 12 coalesced float4 partial stores; no atomics anywhere.
// ---------------------------------------------------------------------------
__global__ __launch_bounds__(256) void enc_fused(
    const float* __restrict__ X,   // (8192, 2) positions
    const float* __restrict__ Y,   // (8192, 2) labels
    float* __restrict__ ws)        // partials [tile*128 + s][12288]
{
    __shared__ float4 Ex4[CI][32];   // [i][jf] : j = 4*jf+tj     (32 KB)
    __shared__ float4 Ey4[CI][8];    // [i][kf] : k = kb+4*kf+tk  (8 KB)
    __shared__ float2 W2[CI];        // labels                    (0.5 KB)

    const int t    = threadIdx.x;
    const int b    = blockIdx.x;
    const int tile = b & 3;          // k band: kb = tile*32
    const int sidx = b >> 2;         // split 0..127
    const int c0   = sidx * CI;
    const int kb   = tile * BK;

    const float sc   = 0.84932184f;  // sqrt(0.5 * log2(e))
    const float step = 4.0f / 127.0f;
    const float ss   = step * sc;

    const float2* X2 = (const float2*)X;
    const float2* Y2 = (const float2*)Y;

    // ---- stage Ex: lane-consecutive float4 writes (conflict-free).
    //      r-th pass: i = r*8 + (t>>5), jf = t&31 -> 4 exps.
#pragma unroll
    for (int r = 0; r < 8; ++r) {
        const int   i  = r * 8 + (t >> 5);
        const int   jf = t & 31;
        const float sx = X2[c0 + i].x * sc;
        float d = (-2.0f + step * (float)(4 * jf)) * sc - sx;
        float4 v;
        v.x = fast_exp2(-d * d); d += ss;
        v.y = fast_exp2(-d * d); d += ss;
        v.z = fast_exp2(-d * d); d += ss;
        v.w = fast_exp2(-d * d);
        Ex4[i][jf] = v;
    }
    // ---- stage Ey: i = r*32 + (t>>3), kf = t&7 -> 4 exps. gy falls with k.
#pragma unroll
    for (int r = 0; r < 2; ++r) {
        const int   i  = r * 32 + (t >> 3);
        const int   kf = t & 7;
        const float sy = X2[c0 + i].y * sc;
        float d = (2.0f - step * (float)(kb + 4 * kf)) * sc - sy;
        float4 v;
        v.x = fast_exp2(-d * d); d -= ss;
        v.y = fast_exp2(-d * d); d -= ss;
        v.z = fast_exp2(-d * d); d -= ss;
        v.w = fast_exp2(-d * d);
        Ey4[i][kf] = v;
    }
    if (t < CI) W2[t] = Y2[c0 + t];
    __syncthreads();

    // ---- rank-1 accumulation: 48 independent fma chains.
    const int jf = t & 31;
    const int kf = t >> 5;

    float acc[48];                   // [cq = c*4+tk][tj]
#pragma unroll
    for (int z = 0; z < 48; ++z) acc[z] = 0.0f;

#pragma unroll 4
    for (int i = 0; i < CI; ++i) {
        const float4 a = Ex4[i][jf];     // per-lane b128, conflict-free
        const float4 e = Ey4[i][kf];     // 2 addrs/wave -> broadcast
        const float2 w = W2[i];          // uniform b64
        const float av[4] = {a.x, a.y, a.z, a.w};
        const float ev[4] = {e.x, e.y, e.z, e.w};
#pragma unroll
        for (int tk = 0; tk < 4; ++tk) {
            const float et = ev[tk];
            const float m1 = et * w.x;
            const float m2 = et * w.y;
#pragma unroll
            for (int tj = 0; tj < 4; ++tj) {
                acc[(tk)*4      + tj] = fmaf(av[tj], et, acc[(tk)*4      + tj]);
                acc[(4 + tk)*4  + tj] = fmaf(av[tj], m1, acc[(4 + tk)*4  + tj]);
                acc[(8 + tk)*4  + tj] = fmaf(av[tj], m2, acc[(8 + tk)*4  + tj]);
            }
        }
    }

    // ---- coalesced partial store: P[h], h = cq*1024 + 4*t + tj
    float* P = ws + (size_t)(tile * NSPLIT + sidx) * PBLK;
#pragma unroll
    for (int cq = 0; cq < 12; ++cq) {
        float4 v = make_float4(acc[cq*4+0], acc[cq*4+1], acc[cq*4+2], acc[cq*4+3]);
        ((float4*)(P + cq * 1024))[t] = v;
    }
}

// ---------------------------------------------------------------------------
// Reduce + normalize. Thread <-> (tile, h0), h0 = tk*1024 + 4*u + tj where u
// was the writer thread. 3 channel streams at h0 + c*4096, fully coalesced,
// 384 independent loads deep. 256 blocks x 64 -> 1 wave/CU streaming 25 MB.
// ---------------------------------------------------------------------------
__global__ __launch_bounds__(64) void reduce_norm(
    const float* __restrict__ ws, float* __restrict__ out)
{
    const int flat = blockIdx.x * 64 + threadIdx.x;  // 0..16383
    const int tile = flat >> 12;
    const int h0   = flat & 4095;

    const float* base = ws + (size_t)tile * NSPLIT * PBLK + h0;
    float s0 = 0.f, s1 = 0.f, s2 = 0.f;
#pragma unroll 8
    for (int s = 0; s < NSPLIT; ++s) {
        const float* p = base + (size_t)s * PBLK;
        s0 += p[0];
        s1 += p[4096];
        s2 += p[8192];
    }

    const int tk = h0 >> 10;
    const int u  = (h0 >> 2) & 255;
    const int tj = h0 & 3;
    const int jf = u & 31, kf = u >> 5;
    const int k  = tile * BK + kf * 4 + tk;
    const int j  = jf * 4 + tj;
    const int g  = k * 128 + j;

    const float inv = 1.0f / s0;
    out[g]               = s0;
    out[G_TOTAL + g]     = s1 * inv;
    out[2 * G_TOTAL + g] = s2 * inv;
}

// ---------------------------------------------------------------------------
extern "C" void kernel_launch(void* const* d_in, const int* in_sizes, int n_in,
                              void* d_out, int out_size, void* d_ws, size_t ws_size,
                              hipStream_t stream) {
    const float* X = (const float*)d_in[0];
    const float* Y = (const float*)d_in[1];
    float* out = (float*)d_out;
    float* ws  = (float*)d_ws;

    enc_fused<<<512, 256, 0, stream>>>(X, Y, ws);       // 2 blocks/CU
    reduce_norm<<<256, 64, 0, stream>>>(ws, out);
}

// Round 7
// 75.573 us; speedup vs baseline: 1.6011x; 1.1268x over previous
//
#include <hip/hip_runtime.h>

#define G_TOTAL 16384            // 128 x 128 grid
#define NPTS    8192
#define CI      64               // context points per block
#define NSPLIT  128              // 8192 / CI
#define BK      32               // k extent per block tile
#define PPLANES 24               // (cq 0..11) x (tj-pair 0..1) planes of 256 half2
// ws: partials as half2 [4 tiles][128 s][24 planes][256] = 12.6 MB

typedef _Float16 h2 __attribute__((ext_vector_type(2)));

// Raw v_exp_f32 — args in [-30, 0]: no denormal/range fixup needed.
__device__ __forceinline__ float fast_exp2(float x) {
#if __has_builtin(__builtin_amdgcn_exp2f)
    return __builtin_amdgcn_exp2f(x);
#else
    float r; asm("v_exp_f32 %0, %1" : "=v"(r) : "v"(x)); return r;
#endif
}

// ---------------------------------------------------------------------------
// Fused factorized kernel (R6 core, fp16-partial epilogue).
// w(j,k,i) = Ex(j,i)*Ey(k,i); channels {1,y0,y1}. Thread tile 4j x 4k x 3c.
// R6 post-mortem: inner loop ~balanced (LDS 240cy vs VALU 224cy per CU-i);
// the fat is 24MB fp32 partial traffic + 1-wave/block reduce. This round:
// partials packed to half2 (RNE converts, unbiased; partial magnitude <= 64,
// fp32 cross-split accumulation in reduce) -> 12.6 MB total.
// ---------------------------------------------------------------------------
__global__ __launch_bounds__(256) void enc_fused(
    const float* __restrict__ X,   // (8192, 2) positions
    const float* __restrict__ Y,   // (8192, 2) labels
    h2* __restrict__ wsP)          // partials [tile][s][plane][256]
{
    __shared__ float4 Ex4[CI][32];   // [i][jf] : j = 4*jf+tj     (32 KB)
    __shared__ float4 Ey4[CI][8];    // [i][kf] : k = kb+4*kf+tk  (8 KB)
    __shared__ float2 W2[CI];        // labels                    (0.5 KB)

    const int t    = threadIdx.x;
    const int b    = blockIdx.x;
    const int tile = b & 3;          // k band: kb = tile*32
    const int sidx = b >> 2;         // split 0..127
    const int c0   = sidx * CI;
    const int kb   = tile * BK;

    const float sc   = 0.84932184f;  // sqrt(0.5 * log2(e))
    const float step = 4.0f / 127.0f;
    const float ss   = step * sc;

    const float2* X2 = (const float2*)X;
    const float2* Y2 = (const float2*)Y;

    // ---- stage Ex: lane-consecutive float4 writes (conflict-free).
#pragma unroll
    for (int r = 0; r < 8; ++r) {
        const int   i  = r * 8 + (t >> 5);
        const int   jf = t & 31;
        const float sx = X2[c0 + i].x * sc;
        float d = (-2.0f + step * (float)(4 * jf)) * sc - sx;
        float4 v;
        v.x = fast_exp2(-d * d); d += ss;
        v.y = fast_exp2(-d * d); d += ss;
        v.z = fast_exp2(-d * d); d += ss;
        v.w = fast_exp2(-d * d);
        Ex4[i][jf] = v;
    }
    // ---- stage Ey: i = r*32 + (t>>3), kf = t&7. gy falls with k.
#pragma unroll
    for (int r = 0; r < 2; ++r) {
        const int   i  = r * 32 + (t >> 3);
        const int   kf = t & 7;
        const float sy = X2[c0 + i].y * sc;
        float d = (2.0f - step * (float)(kb + 4 * kf)) * sc - sy;
        float4 v;
        v.x = fast_exp2(-d * d); d -= ss;
        v.y = fast_exp2(-d * d); d -= ss;
        v.z = fast_exp2(-d * d); d -= ss;
        v.w = fast_exp2(-d * d);
        Ey4[i][kf] = v;
    }
    if (t < CI) W2[t] = Y2[c0 + t];
    __syncthreads();

    // ---- rank-1 accumulation: 48 independent fma chains.
    const int jf = t & 31;
    const int kf = t >> 5;

    float acc[48];                   // [(c*4+tk)][tj]
#pragma unroll
    for (int z = 0; z < 48; ++z) acc[z] = 0.0f;

#pragma unroll 4
    for (int i = 0; i < CI; ++i) {
        const float4 a = Ex4[i][jf];     // per-lane b128, conflict-free
        const float4 e = Ey4[i][kf];     // 2 addrs/wave -> broadcast
        const float2 w = W2[i];          // uniform b64
        const float av[4] = {a.x, a.y, a.z, a.w};
        const float ev[4] = {e.x, e.y, e.z, e.w};
#pragma unroll
        for (int tk = 0; tk < 4; ++tk) {
            const float et = ev[tk];
            const float m1 = et * w.x;
            const float m2 = et * w.y;
#pragma unroll
            for (int tj = 0; tj < 4; ++tj) {
                acc[(tk)*4      + tj] = fmaf(av[tj], et, acc[(tk)*4      + tj]);
                acc[(4 + tk)*4  + tj] = fmaf(av[tj], m1, acc[(4 + tk)*4  + tj]);
                acc[(8 + tk)*4  + tj] = fmaf(av[tj], m2, acc[(8 + tk)*4  + tj]);
            }
        }
    }

    // ---- fp16 packed partial store: plane p = cq*2 + tjp, lane-consecutive.
    h2* P = wsP + (size_t)((tile * NSPLIT + sidx) * PPLANES) * 256 + t;
#pragma unroll
    for (int cq = 0; cq < 12; ++cq) {
        h2 lo, hi;                       // RNE converts (unbiased)
        lo.x = (_Float16)acc[cq*4 + 0];  lo.y = (_Float16)acc[cq*4 + 1];
        hi.x = (_Float16)acc[cq*4 + 2];  hi.y = (_Float16)acc[cq*4 + 3];
        P[(cq*2 + 0) * 256] = lo;
        P[(cq*2 + 1) * 256] = hi;
    }
}

// ---------------------------------------------------------------------------
// Reduce + normalize, v2: 256 blocks x 256 threads (4 waves/block, every CU
// busy), 8-way split over s with LDS combine. Thread handles output PAIR
// m = bx*32 + (t&31) for split range (t>>5)*16..+16; fp32 accumulation.
// ---------------------------------------------------------------------------
__global__ __launch_bounds__(256) void reduce_norm(
    const h2* __restrict__ wsP, float* __restrict__ out)
{
    __shared__ float2 sm[3][8][32];      // [c][sq][pr] : 6 KB

    const int t  = threadIdx.x;
    const int pr = t & 31;
    const int sq = t >> 5;
    const int m  = blockIdx.x * 32 + pr;     // pair index 0..8191

    const int tp   = m & 1;
    const int u    = (m >> 1) & 255;         // writer thread
    const int tk   = (m >> 9) & 3;
    const int tile = m >> 11;

    const int p0 = (0 * 4 + tk) * 2 + tp;    // channel planes
    const int p1 = (1 * 4 + tk) * 2 + tp;
    const int p2 = (2 * 4 + tk) * 2 + tp;

    float2 s0 = make_float2(0.f, 0.f);
    float2 s1 = make_float2(0.f, 0.f);
    float2 s2 = make_float2(0.f, 0.f);

#pragma unroll 4
    for (int s = sq * 16; s < sq * 16 + 16; ++s) {
        const h2* q = wsP + (size_t)((tile * NSPLIT + s) * PPLANES) * 256 + u;
        const h2 a = q[p0 * 256];
        const h2 b = q[p1 * 256];
        const h2 c = q[p2 * 256];
        s0.x += (float)a.x;  s0.y += (float)a.y;
        s1.x += (float)b.x;  s1.y += (float)b.y;
        s2.x += (float)c.x;  s2.y += (float)c.y;
    }
    sm[0][sq][pr] = s0;
    sm[1][sq][pr] = s1;
    sm[2][sq][pr] = s2;
    __syncthreads();

    if (t < 32) {
        float2 f0 = make_float2(0.f, 0.f);
        float2 f1 = make_float2(0.f, 0.f);
        float2 f2 = make_float2(0.f, 0.f);
#pragma unroll
        for (int w = 0; w < 8; ++w) {
            f0.x += sm[0][w][t].x;  f0.y += sm[0][w][t].y;
            f1.x += sm[1][w][t].x;  f1.y += sm[1][w][t].y;
            f2.x += sm[2][w][t].x;  f2.y += sm[2][w][t].y;
        }
        const int mm   = blockIdx.x * 32 + t;
        const int tpp  = mm & 1;
        const int uu   = (mm >> 1) & 255;
        const int tkk  = (mm >> 9) & 3;
        const int til  = mm >> 11;
        const int jff  = uu & 31, kff = uu >> 5;
        const int k    = til * BK + kff * 4 + tkk;
        const int j    = jff * 4 + tpp * 2;
        const int g    = k * 128 + j;

        const float i0 = 1.0f / f0.x;
        const float i1 = 1.0f / f0.y;
        *(float2*)(out + g)               = make_float2(f0.x,      f0.y);
        *(float2*)(out + G_TOTAL + g)     = make_float2(f1.x * i0, f1.y * i1);
        *(float2*)(out + 2*G_TOTAL + g)   = make_float2(f2.x * i0, f2.y * i1);
    }
}

// ---------------------------------------------------------------------------
extern "C" void kernel_launch(void* const* d_in, const int* in_sizes, int n_in,
                              void* d_out, int out_size, void* d_ws, size_t ws_size,
                              hipStream_t stream) {
    const float* X = (const float*)d_in[0];
    const float* Y = (const float*)d_in[1];
    float* out = (float*)d_out;
    h2*   wsP = (h2*)d_ws;

    enc_fused<<<512, 256, 0, stream>>>(X, Y, wsP);     // 2 blocks/CU
    reduce_norm<<<256, 256, 0, stream>>>(wsP, out);
}